// Round 3
// baseline (870.641 us; speedup 1.0000x reference)
//
#include <hip/hip_runtime.h>
#include <hip/hip_bf16.h>
#include <stdint.h>

// ---------------------------------------------------------------------------
// AdaptiveAngleConv: 5 angles of (bilinear deform-sample -> 3x3 conv)
// x: (2,256,64,64) f32, weight: (256,256,3,3) f32
// out: 5 x (2,256,190,190) f32 concatenated
// Conv = implicit GEMM, BM=128px x BN=128oc, BK=32, ring-4 LDS (64KB),
// prefetch distance 3, counted vmcnt(8), 1 barrier/K-tile, setprio.
// 2 blocks/CU co-residency (67.6KB static LDS).
// ---------------------------------------------------------------------------

#define S2F 1.41421356237309515f

__constant__ float c_ox[5][9] = {
  {0.f,0.f,0.f,0.f,0.f,0.f,0.f,0.f,0.f},
  {1.f-S2F, 1.f-S2F*0.5f, 1.f, -S2F*0.5f, 0.f, S2F*0.5f, -1.f, S2F*0.5f-1.f, S2F-1.f},
  {0.f,1.f,2.f,-1.f,0.f,1.f,-2.f,-1.f,0.f},
  {1.f, 1.f+S2F*0.5f, 1.f+S2F, -S2F*0.5f, 0.f, S2F*0.5f, -1.f-S2F, -1.f-S2F*0.5f, -1.f},
  {2.f,2.f,2.f,0.f,0.f,0.f,-2.f,-2.f,-2.f}
};
__constant__ float c_oy[5][9] = {
  {0.f,0.f,0.f,0.f,0.f,0.f,0.f,0.f,0.f},
  {1.f, S2F*0.5f, S2F-1.f, 1.f-S2F*0.5f, 0.f, S2F*0.5f-1.f, 1.f-S2F, -S2F*0.5f, -1.f},
  {2.f,1.f,0.f,1.f,0.f,-1.f,0.f,-1.f,-2.f},
  {1.f+S2F, S2F*0.5f, -1.f, 1.f+S2F*0.5f, 0.f, -1.f-S2F*0.5f, 1.f, -S2F*0.5f, 1.f+S2F},
  {2.f,0.f,-2.f,2.f,0.f,-2.f,2.f,0.f,-2.f}
};

typedef __bf16 bf16x8_t __attribute__((ext_vector_type(8)));
typedef float f32x4_t __attribute__((ext_vector_type(4)));

typedef const __attribute__((address_space(1))) void* as1cp;
typedef __attribute__((address_space(3))) void* as3p;

__device__ __forceinline__ void gload16(const void* g, void* l) {
  __builtin_amdgcn_global_load_lds((as1cp)g, (as3p)l, 16, 0, 0);
}

// x NCHW (2,256,64,64) -> xT NHWC (2,64,64,256) f32
__global__ void k_transpose(const float* __restrict__ x, float* __restrict__ xT) {
  const int v = blockIdx.x, u = blockIdx.y, b = blockIdx.z;
  const int ic = threadIdx.x;
  xT[(((b*64 + u)*64 + v)*256) + ic] =
      x[(((b*256 + ic)*64 + u)*64) + v];
}

// weight OIHW (256,256,3,3) f32 -> wb (9,256,256)=[t][oc][ic] bf16
__global__ void k_wconv(const float* __restrict__ w, __hip_bfloat16* __restrict__ wb) {
  const int tid = blockIdx.x*256 + threadIdx.x;   // < 9*256*256
  const int t = tid >> 16;
  const int rem = tid & 65535;
  const int oc = rem >> 8;
  const int ic = rem & 255;
  wb[tid] = __float2bfloat16(w[(oc*256 + ic)*9 + t]);
}

// bilinear deform-sample -> xo bf16 NHWC [(a)][b][192][192][256]
__global__ void k_sample(const float* __restrict__ xT,
                         __hip_bfloat16* __restrict__ xo, int a0)
{
  const int aidx = a0 + blockIdx.z;
  __hip_bfloat16* xoa = xo + (size_t)blockIdx.z * (2ull*192*192*256);

  const int tid = threadIdx.x;           // 256
  const int ic = (tid & 63) * 4;
  const int j = blockIdx.x*4 + (tid >> 6);
  const int i = blockIdx.y;

  const int a = i / 3, r = i - 3*a;
  const int bc = j / 3, s = j - 3*bc;
  const int n = r*3 + s;
  const float px = (float)(a + r) + c_ox[aidx][n];
  const float py = (float)(bc + s) + c_oy[aidx][n];
  const float fx = floorf(px), fy = floorf(py);
  const float pxc = fminf(fmaxf(px, 0.f), 65.f);
  const float pyc = fminf(fmaxf(py, 0.f), 65.f);
  const int qlx = (int)fminf(fmaxf(fx,      0.f), 65.f);
  const int qrx = (int)fminf(fmaxf(fx + 1.f, 0.f), 65.f);
  const int qly = (int)fminf(fmaxf(fy,      0.f), 65.f);
  const int qry = (int)fminf(fmaxf(fy + 1.f, 0.f), 65.f);
  const float wlx = 1.f + (float)qlx - pxc;
  const float wrx = 1.f - (float)qrx + pxc;
  const float wly = 1.f + (float)qly - pyc;
  const float wry = 1.f - (float)qry + pyc;
  const float glt = wlx*wly, grb = wrx*wry, glb = wlx*wry, grt = wrx*wly;

  const bool inxl = (qlx >= 1) && (qlx <= 64);
  const bool inxr = (qrx >= 1) && (qrx <= 64);
  const bool inyl = (qly >= 1) && (qly <= 64);
  const bool inyr = (qry >= 1) && (qry <= 64);

  const f32x4_t zero = (f32x4_t){0.f,0.f,0.f,0.f};
  #pragma unroll
  for (int b = 0; b < 2; ++b) {
    const float* xb = xT + (size_t)b * (64*64*256);
    f32x4_t vlt = (inxl && inyl) ? *(const f32x4_t*)&xb[((qlx-1)*64 + (qly-1))*256 + ic] : zero;
    f32x4_t vrb = (inxr && inyr) ? *(const f32x4_t*)&xb[((qrx-1)*64 + (qry-1))*256 + ic] : zero;
    f32x4_t vlb = (inxl && inyr) ? *(const f32x4_t*)&xb[((qlx-1)*64 + (qry-1))*256 + ic] : zero;
    f32x4_t vrt = (inxr && inyl) ? *(const f32x4_t*)&xb[((qrx-1)*64 + (qly-1))*256 + ic] : zero;
    ushort4 pk;
    float v0 = glt*vlt[0] + grb*vrb[0] + glb*vlb[0] + grt*vrt[0];
    float v1 = glt*vlt[1] + grb*vrb[1] + glb*vlb[1] + grt*vrt[1];
    float v2 = glt*vlt[2] + grb*vrb[2] + glb*vlb[2] + grt*vrt[2];
    float v3 = glt*vlt[3] + grb*vrb[3] + glb*vlb[3] + grt*vrt[3];
    pk.x = __hip_bfloat16_raw(__float2bfloat16(v0)).x;
    pk.y = __hip_bfloat16_raw(__float2bfloat16(v1)).x;
    pk.z = __hip_bfloat16_raw(__float2bfloat16(v2)).x;
    pk.w = __hip_bfloat16_raw(__float2bfloat16(v3)).x;
    *(ushort4*)&xoa[(((size_t)b*192 + i)*192 + j)*256 + ic] = pk;
  }
}

// ---------------------------------------------------------------------------
// conv: implicit GEMM. grid.x = nab*576 (XCD-swizzled, bijective chunking).
// Block: 128 px (2 rows x 64 cols) x 128 oc; K = 9 taps x 256 ic, BK=32.
// Ring-4 LDS: sA 4x8KB @0, sB 4x8KB @32768; epilogue f32[128][132] overlaps.
// ---------------------------------------------------------------------------
__global__ __launch_bounds__(256, 2) void k_conv3(
    const __hip_bfloat16* __restrict__ xo,   // [ab][192][192][256] bf16
    const __hip_bfloat16* __restrict__ wb,   // [9][256][256] bf16 (t,oc,ic)
    float* __restrict__ out)                 // + ab*9241600 : [256][190][190]
{
  __shared__ __align__(16) char smem[67584];
  char* const sA = smem;            // 4 slots x 8192
  char* const sB = smem + 32768;    // 4 slots x 8192

  const int nblk = gridDim.x;
  const int id = blockIdx.x;
  const int qq = nblk >> 3, rr = nblk & 7;
  const int xcd = id & 7, pos = id >> 3;
  const int swz = (xcd < rr ? xcd*(qq+1) : rr*(qq+1) + (xcd-rr)*qq) + pos;
  const int nt = swz & 1;
  const int rest = swz >> 1;
  const int ab = rest / 288;
  const int mt = rest - ab*288;
  const int q  = mt / 3;
  const int ct = mt - q*3;
  const int i0 = q*2, j0 = ct*64;

  const int tid = threadIdx.x;
  const int w = tid >> 6, l = tid & 63;
  const int wm = w >> 1, wn = w & 1;

  const char* xob = (const char*)(xo + (size_t)ab * 9437184u);
  const char* wbc = (const char*)wb;

  // --- staging constants: lane l -> chunk row l>>2, swizzled 16B slot l&3 ---
  const int px0   = w*16 + (l >> 2);                    // 0..63 (di=0 chunk)
  const int swzic = ((l & 3) ^ ((l >> 3) & 3)) * 8;     // ic-elem offset
  const int ja0   = j0 + px0;
  const int boc0  = ((nt*128 + px0)*256 + swzic) * 2;
  const int boc1  = ((nt*128 + px0 + 64)*256 + swzic) * 2;
  const int wofs  = w*1024, wofs2 = (w+4)*1024;

  // --- frag read offsets (matching swizzle: slot = ks ^ ((row>>1)&3)) ---
  const int fsw = ((l >> 4) ^ ((l >> 1) & 3)) * 16;
  int aoffs[4], boffs[4];
  #pragma unroll
  for (int f = 0; f < 4; ++f) {
    aoffs[f] = (wm*64 + f*16 + (l & 15))*64 + fsw;
    boffs[f] = (wn*64 + f*16 + (l & 15))*64 + fsw;
  }

  auto stage = [&](int T2) {
    const int t = T2 >> 3;
    const int icg32 = (T2 & 7) << 5;
    const int ki = (t >= 6) ? 2 : ((t >= 3) ? 1 : 0);
    const int kj = t - ki*3;
    char* dA = sA + (T2 & 3)*8192;
    char* dB = sB + (T2 & 3)*8192;
    int j1 = ja0 + kj; j1 = (j1 > 191) ? 191 : j1;
    int i1 = i0 + ki;
    int i2 = i1 + 1;   i2 = (i2 > 191) ? 191 : i2;
    i1 = (i1 > 191) ? 191 : i1;
    gload16(xob + ((((i1*192 + j1) << 8) + icg32 + swzic) << 1), dA + wofs);
    gload16(xob + ((((i2*192 + j1) << 8) + icg32 + swzic) << 1), dA + wofs2);
    const char* bs = wbc + (((t << 16) + icg32) << 1);
    gload16(bs + boc0, dB + wofs);
    gload16(bs + boc1, dB + wofs2);
  };

  f32x4_t acc[4][4];
  #pragma unroll
  for (int mf = 0; mf < 4; ++mf)
    #pragma unroll
    for (int nf = 0; nf < 4; ++nf)
      acc[mf][nf] = (f32x4_t){0.f, 0.f, 0.f, 0.f};

  // prologue: tiles 0,1,2 in flight (12 loads/thread, tile-ordered)
  stage(0); stage(1); stage(2);

  for (int T = 0; T < 72; ++T) {
    if (T < 70)       { asm volatile("s_waitcnt vmcnt(8)" ::: "memory"); }
    else if (T == 70) { asm volatile("s_waitcnt vmcnt(4)" ::: "memory"); }
    else              { asm volatile("s_waitcnt vmcnt(0)" ::: "memory"); }
    __builtin_amdgcn_s_barrier();
    __builtin_amdgcn_sched_barrier(0);

    const char* ab_ = sA + (T & 3)*8192;
    const char* bb_ = sB + (T & 3)*8192;
    bf16x8_t af[4], bq[4];
    #pragma unroll
    for (int f = 0; f < 4; ++f) af[f] = *(const bf16x8_t*)(ab_ + aoffs[f]);
    #pragma unroll
    for (int f = 0; f < 4; ++f) bq[f] = *(const bf16x8_t*)(bb_ + boffs[f]);

    if (T < 69) stage(T + 3);

    asm volatile("s_waitcnt lgkmcnt(0)" ::: "memory");
    __builtin_amdgcn_sched_barrier(0);
    __builtin_amdgcn_s_setprio(1);
    #pragma unroll
    for (int mf = 0; mf < 4; ++mf)
      #pragma unroll
      for (int nf = 0; nf < 4; ++nf)
        acc[mf][nf] = __builtin_amdgcn_mfma_f32_16x16x32_bf16(
            af[mf], bq[nf], acc[mf][nf], 0, 0, 0);
    __builtin_amdgcn_s_setprio(0);
  }

  // --- epilogue: stage C through LDS f32[128oc][132] for coalesced stores ---
  __syncthreads();                      // all ring reads/MFMA inputs consumed
  float* eps = (float*)smem;
  #pragma unroll
  for (int mf = 0; mf < 4; ++mf)
    #pragma unroll
    for (int nf = 0; nf < 4; ++nf)
      *(f32x4_t*)&eps[(wn*64 + nf*16 + (l & 15))*132 +
                      wm*64 + mf*16 + (l >> 4)*4] = acc[mf][nf];
  __syncthreads();

  const int ocr = tid >> 1, half = tid & 1;
  const int iS = i0 + half;
  const int jend = (ct == 2) ? 62 : 64;
  if (iS < 190) {
    float* dst = out + (size_t)ab*9241600u + (size_t)(nt*128 + ocr)*36100u
                 + iS*190 + j0;
    const float* src = eps + ocr*132 + half*64;
    for (int jc = 0; jc < jend; jc += 2)
      *(float2*)(dst + jc) = make_float2(src[jc], src[jc + 1]);
  }
}

extern "C" void kernel_launch(void* const* d_in, const int* in_sizes, int n_in,
                              void* d_out, int out_size, void* d_ws, size_t ws_size,
                              hipStream_t stream)
{
  const float* x = (const float*)d_in[0];
  const float* w = (const float*)d_in[1];
  float* out = (float*)d_out;

  char* ws = (char*)d_ws;
  float*          xT = (float*)ws;                         // 8,388,608 B
  __hip_bfloat16* wb = (__hip_bfloat16*)(ws + 8388608);    // 1,179,648 B
  __hip_bfloat16* xo = (__hip_bfloat16*)(ws + 9568256);    // 5 or 1 x 37,748,736 B

  const bool merged = (ws_size >= 198311936ull);

  k_transpose<<<dim3(64, 64, 2), 256, 0, stream>>>(x, xT);
  k_wconv<<<2304, 256, 0, stream>>>(w, wb);

  if (merged) {
    k_sample<<<dim3(48, 192, 5), 256, 0, stream>>>(xT, xo, 0);
    k_conv3<<<5760, 256, 0, stream>>>(xo, wb, out);
  } else {
    for (int aidx = 0; aidx < 5; ++aidx) {
      k_sample<<<dim3(48, 192, 1), 256, 0, stream>>>(xT, xo, aidx);
      k_conv3<<<1152, 256, 0, stream>>>(xo, wb, out + (size_t)aidx * 18483200u);
    }
  }
}

// Round 4
// 826.276 us; speedup vs baseline: 1.0537x; 1.0537x over previous
//
#include <hip/hip_runtime.h>
#include <hip/hip_bf16.h>
#include <stdint.h>

// ---------------------------------------------------------------------------
// AdaptiveAngleConv: 5 angles of (bilinear deform-sample -> 3x3 conv)
// x: (2,256,64,64) f32, weight: (256,256,3,3) f32
// out: 5 x (2,256,190,190) f32 concatenated
// Conv = implicit GEMM, m201-style 8-phase schedule:
//   BM=256px x BN=256oc, BK=64, 512 thr / 8 waves (2Mx4N), dbuf K-tiles,
//   counted vmcnt(2) at phases 4/8 only, raw barriers, setprio around MFMA.
// ---------------------------------------------------------------------------

#define S2F 1.41421356237309515f

__constant__ float c_ox[5][9] = {
  {0.f,0.f,0.f,0.f,0.f,0.f,0.f,0.f,0.f},
  {1.f-S2F, 1.f-S2F*0.5f, 1.f, -S2F*0.5f, 0.f, S2F*0.5f, -1.f, S2F*0.5f-1.f, S2F-1.f},
  {0.f,1.f,2.f,-1.f,0.f,1.f,-2.f,-1.f,0.f},
  {1.f, 1.f+S2F*0.5f, 1.f+S2F, -S2F*0.5f, 0.f, S2F*0.5f, -1.f-S2F, -1.f-S2F*0.5f, -1.f},
  {2.f,2.f,2.f,0.f,0.f,0.f,-2.f,-2.f,-2.f}
};
__constant__ float c_oy[5][9] = {
  {0.f,0.f,0.f,0.f,0.f,0.f,0.f,0.f,0.f},
  {1.f, S2F*0.5f, S2F-1.f, 1.f-S2F*0.5f, 0.f, S2F*0.5f-1.f, 1.f-S2F, -S2F*0.5f, -1.f},
  {2.f,1.f,0.f,1.f,0.f,-1.f,0.f,-1.f,-2.f},
  {1.f+S2F, S2F*0.5f, -1.f, 1.f+S2F*0.5f, 0.f, -1.f-S2F*0.5f, 1.f, -S2F*0.5f, 1.f+S2F},
  {2.f,0.f,-2.f,2.f,0.f,-2.f,2.f,0.f,-2.f}
};

typedef __bf16 bf16x8_t __attribute__((ext_vector_type(8)));
typedef float f32x4_t __attribute__((ext_vector_type(4)));

typedef const __attribute__((address_space(1))) void* as1cp;
typedef __attribute__((address_space(3))) void* as3p;

__device__ __forceinline__ void gload16(const void* g, void* l) {
  __builtin_amdgcn_global_load_lds((as1cp)g, (as3p)l, 16, 0, 0);
}

// x NCHW (2,256,64,64) -> xT NHWC (2,64,64,256) f32
__global__ void k_transpose(const float* __restrict__ x, float* __restrict__ xT) {
  const int v = blockIdx.x, u = blockIdx.y, b = blockIdx.z;
  const int ic = threadIdx.x;
  xT[(((b*64 + u)*64 + v)*256) + ic] =
      x[(((b*256 + ic)*64 + u)*64) + v];
}

// weight OIHW (256,256,3,3) f32 -> wb (9,256,256)=[t][oc][ic] bf16
__global__ void k_wconv(const float* __restrict__ w, __hip_bfloat16* __restrict__ wb) {
  const int tid = blockIdx.x*256 + threadIdx.x;   // < 9*256*256
  const int t = tid >> 16;
  const int rem = tid & 65535;
  const int oc = rem >> 8;
  const int ic = rem & 255;
  wb[tid] = __float2bfloat16(w[(oc*256 + ic)*9 + t]);
}

// bilinear deform-sample -> xo bf16 NHWC [(a)][b][192][192][256]
__global__ void k_sample(const float* __restrict__ xT,
                         __hip_bfloat16* __restrict__ xo, int a0)
{
  const int aidx = a0 + blockIdx.z;
  __hip_bfloat16* xoa = xo + (size_t)blockIdx.z * (2ull*192*192*256);

  const int tid = threadIdx.x;           // 256
  const int ic = (tid & 63) * 4;
  const int j = blockIdx.x*4 + (tid >> 6);
  const int i = blockIdx.y;

  const int a = i / 3, r = i - 3*a;
  const int bc = j / 3, s = j - 3*bc;
  const int n = r*3 + s;
  const float px = (float)(a + r) + c_ox[aidx][n];
  const float py = (float)(bc + s) + c_oy[aidx][n];
  const float fx = floorf(px), fy = floorf(py);
  const float pxc = fminf(fmaxf(px, 0.f), 65.f);
  const float pyc = fminf(fmaxf(py, 0.f), 65.f);
  const int qlx = (int)fminf(fmaxf(fx,      0.f), 65.f);
  const int qrx = (int)fminf(fmaxf(fx + 1.f, 0.f), 65.f);
  const int qly = (int)fminf(fmaxf(fy,      0.f), 65.f);
  const int qry = (int)fminf(fmaxf(fy + 1.f, 0.f), 65.f);
  const float wlx = 1.f + (float)qlx - pxc;
  const float wrx = 1.f - (float)qrx + pxc;
  const float wly = 1.f + (float)qly - pyc;
  const float wry = 1.f - (float)qry + pyc;
  const float glt = wlx*wly, grb = wrx*wry, glb = wlx*wry, grt = wrx*wly;

  const bool inxl = (qlx >= 1) && (qlx <= 64);
  const bool inxr = (qrx >= 1) && (qrx <= 64);
  const bool inyl = (qly >= 1) && (qly <= 64);
  const bool inyr = (qry >= 1) && (qry <= 64);

  const f32x4_t zero = (f32x4_t){0.f,0.f,0.f,0.f};
  #pragma unroll
  for (int b = 0; b < 2; ++b) {
    const float* xb = xT + (size_t)b * (64*64*256);
    f32x4_t vlt = (inxl && inyl) ? *(const f32x4_t*)&xb[((qlx-1)*64 + (qly-1))*256 + ic] : zero;
    f32x4_t vrb = (inxr && inyr) ? *(const f32x4_t*)&xb[((qrx-1)*64 + (qry-1))*256 + ic] : zero;
    f32x4_t vlb = (inxl && inyr) ? *(const f32x4_t*)&xb[((qlx-1)*64 + (qry-1))*256 + ic] : zero;
    f32x4_t vrt = (inxr && inyl) ? *(const f32x4_t*)&xb[((qrx-1)*64 + (qly-1))*256 + ic] : zero;
    ushort4 pk;
    float v0 = glt*vlt[0] + grb*vrb[0] + glb*vlb[0] + grt*vrt[0];
    float v1 = glt*vlt[1] + grb*vrb[1] + glb*vlb[1] + grt*vrt[1];
    float v2 = glt*vlt[2] + grb*vrb[2] + glb*vlb[2] + grt*vrt[2];
    float v3 = glt*vlt[3] + grb*vrb[3] + glb*vlb[3] + grt*vrt[3];
    pk.x = __hip_bfloat16_raw(__float2bfloat16(v0)).x;
    pk.y = __hip_bfloat16_raw(__float2bfloat16(v1)).x;
    pk.z = __hip_bfloat16_raw(__float2bfloat16(v2)).x;
    pk.w = __hip_bfloat16_raw(__float2bfloat16(v3)).x;
    *(ushort4*)&xoa[(((size_t)b*192 + i)*192 + j)*256 + ic] = pk;
  }
}

// ---------------------------------------------------------------------------
// 8-phase conv. grid.x = nab*144 (XCD-swizzled). Block: 256px x 256oc.
// LDS map (dynamic, 151552 B):
//   buf0 @ 0      : A0 16K | A1 16K | B0 16K | B1 16K   (tile even)
//   buf1 @ 65536  : same                                 (tile odd)
//   dummy @135168 : 16K (tail staging sink)
//   epilogue reuses [0,133120) as f32[128][260]
// ---------------------------------------------------------------------------
__global__ __launch_bounds__(512, 2) void k_conv4(
    const __hip_bfloat16* __restrict__ xo,   // [ab][192][192][256] bf16
    const __hip_bfloat16* __restrict__ wb,   // [9][256][256] bf16 (t,oc,ic)
    float* __restrict__ out)                 // + ab*9241600 : [256][190][190]
{
  extern __shared__ __align__(16) char smem[];

  const int nblk = gridDim.x;                // multiple of 8
  const int cpx = nblk >> 3;
  const int id = blockIdx.x;
  const int swz = (id & 7)*cpx + (id >> 3);
  const int ab = swz / 144;
  const int rem = swz - ab*144;
  const int q  = rem / 3;                    // 0..47
  const int ct = rem - q*3;                  // 0..2
  const int i0 = q*4, j0 = ct*64;

  const int tid = threadIdx.x;
  const int w = tid >> 6, l = tid & 63;
  const int wm = w >> 2, wn = w & 3;         // 2M x 4N

  const char* xob = (const char*)(xo + (size_t)ab * 9437184u);
  const char* wbc = (const char*)wb;

  // staging constants: lane -> (row = w*8 + l>>3, slot = l&7), rows +0/+64
  const int srow = w*8 + (l >> 3);           // 0..63
  const int sic  = ((l & 7) ^ (srow & 7)) * 8;
  const int wofs = w*1024;

  // frag read offsets: (l&15)*128 + ((ks*4 + (l>>4)) ^ (l&7))*16
  const int aofs0 = (l & 15)*128 + (((l >> 4)    ) ^ (l & 7))*16;
  const int aofs1 = (l & 15)*128 + (((l >> 4) + 4) ^ (l & 7))*16;
  const int bbofs = (wn >> 1)*16384 + (wn & 1)*8192;   // B half/quarter base

  auto stA = [&](int kt, int h, int sbuf) {
    const int ktc = kt > 35 ? 35 : kt;
    char* dst = (kt > 35) ? (smem + 135168) : (smem + sbuf*65536 + h*16384);
    const int tap = ktc >> 2, icg = ktc & 3;
    const int ki = (tap >= 6) ? 2 : ((tap >= 3) ? 1 : 0);
    const int kj = tap - ki*3;
    int i1 = i0 + h*2 + ki;
    int i2 = i1 + 1;
    i1 = i1 > 191 ? 191 : i1;  i2 = i2 > 191 ? 191 : i2;
    int j = j0 + srow + kj;    j  = j  > 191 ? 191 : j;
    const int ic = icg*64 + sic;
    gload16(xob + (size_t)(((i1*192 + j) << 8) + ic)*2, dst + wofs);
    gload16(xob + (size_t)(((i2*192 + j) << 8) + ic)*2, dst + 8192 + wofs);
  };
  auto stB = [&](int kt, int h, int sbuf) {
    const int ktc = kt > 35 ? 35 : kt;
    char* dst = (kt > 35) ? (smem + 135168) : (smem + sbuf*65536 + 32768 + h*16384);
    const int tap = ktc >> 2, icg = ktc & 3;
    const int base = tap*65536 + icg*64 + sic;
    const int oc1 = h*128 + srow;
    gload16(wbc + (size_t)(base + oc1*256)*2, dst + wofs);
    gload16(wbc + (size_t)(base + (oc1 + 64)*256)*2, dst + 8192 + wofs);
  };

  f32x4_t acc[8][4];
  #pragma unroll
  for (int mf = 0; mf < 8; ++mf)
    #pragma unroll
    for (int nf = 0; nf < 4; ++nf)
      acc[mf][nf] = (f32x4_t){0.f, 0.f, 0.f, 0.f};

  // prologue = phases P3..P7 of iter -1 (exact steady-state issue order)
  stB(0, 0, 0); stB(0, 1, 0); stA(0, 0, 0); stA(0, 1, 0); stB(1, 0, 1);
  asm volatile("s_waitcnt vmcnt(2)" ::: "memory");
  __builtin_amdgcn_s_barrier();
  __builtin_amdgcn_sched_barrier(0);

  bf16x8_t bq[4];

#define PH(SBUF, AOFS, MFB, READB, STAGE, GATE)                               \
  {                                                                           \
    const char* Ab = smem + (SBUF)*65536 + wm*16384;                          \
    const char* Bb = smem + (SBUF)*65536 + 32768 + bbofs;                     \
    bf16x8_t af[4];                                                           \
    _Pragma("unroll")                                                         \
    for (int f = 0; f < 4; ++f)                                               \
      af[f] = *(const bf16x8_t*)(Ab + ((MFB) + f)*2048 + (AOFS));             \
    if (READB) {                                                              \
      _Pragma("unroll")                                                       \
      for (int f = 0; f < 4; ++f)                                             \
        bq[f] = *(const bf16x8_t*)(Bb + f*2048 + (AOFS));                     \
    }                                                                         \
    STAGE;                                                                    \
    __builtin_amdgcn_s_barrier();                                             \
    asm volatile("s_waitcnt lgkmcnt(0)" ::: "memory");                        \
    __builtin_amdgcn_sched_barrier(0);                                        \
    __builtin_amdgcn_s_setprio(1);                                            \
    _Pragma("unroll")                                                         \
    for (int mf = 0; mf < 4; ++mf)                                            \
      _Pragma("unroll")                                                       \
      for (int nf = 0; nf < 4; ++nf)                                          \
        acc[(MFB) + mf][nf] = __builtin_amdgcn_mfma_f32_16x16x32_bf16(        \
            af[mf], bq[nf], acc[(MFB) + mf][nf], 0, 0, 0);                    \
    __builtin_amdgcn_s_setprio(0);                                            \
    GATE;                                                                     \
    __builtin_amdgcn_s_barrier();                                             \
    __builtin_amdgcn_sched_barrier(0);                                        \
  }

#define GATE2 asm volatile("s_waitcnt vmcnt(2)" ::: "memory")

  for (int T = 0; T < 18; ++T) {
    const int b1 = 2*T + 1, a2 = 2*T + 2, b2 = 2*T + 3;
    PH(0, aofs0, 0, true,  stB(b1, 1, 1), );        // P0
    PH(0, aofs0, 4, false, stA(b1, 0, 1), );        // P1
    PH(0, aofs1, 0, true,  stA(b1, 1, 1), );        // P2
    PH(0, aofs1, 4, false, stB(a2, 0, 0), GATE2);   // P3 (gate tile b1)
    PH(1, aofs0, 0, true,  stB(a2, 1, 0), );        // P4
    PH(1, aofs0, 4, false, stA(a2, 0, 0), );        // P5
    PH(1, aofs1, 0, true,  stA(a2, 1, 0), );        // P6
    PH(1, aofs1, 4, false, stB(b2, 0, 1), GATE2);   // P7 (gate tile a2)
  }
#undef PH
#undef GATE2

  // --- epilogue: two oc-half passes through LDS f32[128][260] ---
  float* eps = (float*)smem;
  float* outab = out + (size_t)ab * 9241600u;
  const int l15 = l & 15, l4 = l >> 4;
  const int ocr = tid >> 2, di = tid & 3;
  const int iS = i0 + di;
  const int jend = (ct == 2) ? 62 : 64;

  #pragma unroll
  for (int h = 0; h < 2; ++h) {
    __syncthreads();
    if ((wn >> 1) == h) {
      #pragma unroll
      for (int mf = 0; mf < 8; ++mf)
        #pragma unroll
        for (int nf = 0; nf < 4; ++nf)
          *(f32x4_t*)&eps[((wn & 1)*64 + nf*16 + l15)*260 +
                          wm*128 + mf*16 + l4*4] = acc[mf][nf];
    }
    __syncthreads();
    if (iS < 190) {
      float* dst = outab + (size_t)(h*128 + ocr)*36100u + iS*190 + j0;
      const float* src = eps + ocr*260 + di*64;
      for (int jc = 0; jc < jend; jc += 2)
        *(float2*)(dst + jc) = make_float2(src[jc], src[jc + 1]);
    }
  }
}

extern "C" void kernel_launch(void* const* d_in, const int* in_sizes, int n_in,
                              void* d_out, int out_size, void* d_ws, size_t ws_size,
                              hipStream_t stream)
{
  const float* x = (const float*)d_in[0];
  const float* w = (const float*)d_in[1];
  float* out = (float*)d_out;

  char* ws = (char*)d_ws;
  float*          xT = (float*)ws;                         // 8,388,608 B
  __hip_bfloat16* wb = (__hip_bfloat16*)(ws + 8388608);    // 1,179,648 B
  __hip_bfloat16* xo = (__hip_bfloat16*)(ws + 9568256);    // 5 or 1 x 37,748,736 B

  const bool merged = (ws_size >= 198311936ull);

  (void)hipFuncSetAttribute((const void*)k_conv4,
                            hipFuncAttributeMaxDynamicSharedMemorySize, 151552);

  k_transpose<<<dim3(64, 64, 2), 256, 0, stream>>>(x, xT);
  k_wconv<<<2304, 256, 0, stream>>>(w, wb);

  if (merged) {
    k_sample<<<dim3(48, 192, 5), 256, 0, stream>>>(xT, xo, 0);
    k_conv4<<<1440, 512, 151552, stream>>>(xo, wb, out);
  } else {
    for (int aidx = 0; aidx < 5; ++aidx) {
      k_sample<<<dim3(48, 192, 1), 256, 0, stream>>>(xT, xo, aidx);
      k_conv4<<<288, 512, 151552, stream>>>(xo, wb, out + (size_t)aidx * 18483200u);
    }
  }
}